// Round 11
// baseline (827.796 us; speedup 1.0000x reference)
//
#include <hip/hip_runtime.h>

// GraphVAE: GCN-VAE encoder + edge decoder + 50-iter MPM fixed point.
//
// Round-11: KERNEL-BOUNDARY SYNC (graph pipeline). r0-r10 established that
// ANY in-kernel cross-XCD exchange costs ~7us/round (6 protocol shapes,
// bank-conflict fix, and clock heaters all failed to move it; r10 killed
// the clock theory with VALUBusy=61% and no speedup). The harness runs
// kernel_launch under hipGraph capture, so kernel boundaries ARE cheap
// device-wide barriers (runtime-managed release/acquire, ~1-3us/node).
// Structure: 56 graph nodes =
//   enc1 (degrees + x@W1 + GCN/BN/ReLU -> hT)
//   enc2 (hT@W2 + GCN/BN/ReLU -> h2T)
//   enc3 (pool -> z -> t1 -> pair logits -> Bm)
//   prep (A matrix as floats + degA + degB)
//   mpm_step(t) x 50  (plain cached loads/stores; no atomics/spins/asm)
//   fin (final normalization -> out)
// Per-entry arithmetic and ALL reduction orders byte-preserved from r8
// (absmax 0.0 chain). Norm still applied one step late via flags[t].

#define NN 80
#define PBLK 20            // blocks (each owns 4 columns of X)
#define TPB 320            // 5 full waves; lane <-> one (i,a) output
#define RP 84              // LDS row pad: conflict-free b128 row reads
#define NCOLS 13           // encoder: owned feature columns per block

typedef float f4 __attribute__((ext_vector_type(4)));

// ---- ws layout (floats) ----
#define WS_FLAGS 64        // [50*32] per-iter per-block norm partial
#define WS_XB0   2048      // [6400]  MPM ping (row-major X[i*80+a])
#define WS_XB1   8448      // [6400]  MPM pong
#define WS_HT    14848     // [256*80] layer-1 output, transposed
#define WS_H2T   35328     // [256*80] layer-2 output, transposed
#define WS_BM    55808     // [6400]  B = sigmoid(A_hat), diag=1
#define WS_AW    62208     // [6400]  A as float (sym, diag=1)
#define WS_DEGA  68608     // [80]
#define WS_DEGB  68688     // [80]

__device__ __forceinline__ float wave_sum(float v){
  #pragma unroll
  for (int k = 32; k >= 1; k >>= 1) v += __shfl_xor(v, k, 64);
  return v;
}

// GCN aggregate (+self loop) + bias + BatchNorm(train, biased var) + ReLU for
// this block's owned feature columns. inL: LDS [NCOLS][80]. outT: [256][80].
__device__ void gcn_bn_relu(const float* inL, float* outT,
                            const float* bias, const float* gamma, const float* beta,
                            const int* ei, const float* dinv,
                            float* accL, float* colstat, int p, int tid)
{
  for (int u = tid; u < NCOLS*NN; u += TPB) accL[u] = 0.f;
  __syncthreads();
  for (int cl = 0; cl < NCOLS; cl++){
    int c = p + PBLK*cl; if (c >= 256) break;
    const float* col = &inL[cl*NN];
    for (int e = tid; e < 800; e += TPB){
      int sidx = ei[e], didx = ei[800+e];
      atomicAdd(&accL[cl*NN + didx], col[sidx]*dinv[sidx]*dinv[didx]);
    }
  }
  __syncthreads();
  for (int u = tid; u < NCOLS*NN; u += TPB){
    int cl = u/NN, i = u - cl*NN, c = p + PBLK*cl;
    if (c < 256) accL[u] += inL[cl*NN+i]*dinv[i]*dinv[i] + bias[c];
  }
  __syncthreads();
  if (tid < NCOLS){
    int c = p + PBLK*tid;
    if (c < 256){
      const float* a = &accL[tid*NN];
      float m = 0.f;
      for (int i = 0; i < NN; i++) m += a[i];
      m *= (1.0f/NN);
      float v = 0.f;
      for (int i = 0; i < NN; i++){ float d = a[i]-m; v += d*d; }
      v *= (1.0f/NN);
      colstat[2*tid]   = m;
      colstat[2*tid+1] = 1.0f/sqrtf(v + 1e-5f);
    }
  }
  __syncthreads();
  for (int u = tid; u < NCOLS*NN; u += TPB){
    int cl = u/NN, i = u - cl*NN, c = p + PBLK*cl;
    if (c < 256){
      float hv = gamma[c]*(accL[u]-colstat[2*cl])*colstat[2*cl+1] + beta[c];
      outT[c*NN+i] = fmaxf(hv, 0.f);
    }
  }
}

// degrees + dinv into LDS (identical arithmetic to r0-r10's E0)
__device__ void mk_dinv(const int* ei, float* accL, float* dinv, int tid){
  for (int i = tid; i < NN; i += TPB) accL[i] = 1.0f;           // self loop
  __syncthreads();
  for (int e = tid; e < 800; e += TPB) atomicAdd(&accL[ei[800+e]], 1.0f);
  __syncthreads();
  for (int i = tid; i < NN; i += TPB) dinv[i] = 1.0f/sqrtf(accL[i]);
  __syncthreads();
}

// ---------------- enc1: degrees + GEMM1 x@W1 + GCN/BN/ReLU -> hT ------------
__global__ __launch_bounds__(TPB, 1) void enc1(
    const float* __restrict__ x, const int* __restrict__ ei,
    const float* __restrict__ W1, const float* __restrict__ b1,
    const float* __restrict__ g1, const float* __restrict__ bt1,
    float* __restrict__ ws)
{
  const int tid = threadIdx.x, p = blockIdx.x;
  float* hT = ws + WS_HT;
  __shared__ float dinv[NN];
  __shared__ float accL[NCOLS*NN];
  __shared__ float hL[NCOLS*NN];
  __shared__ float colstat[2*NCOLS];

  mk_dinv(ei, accL, dinv, tid);
  for (int u = tid; u < NCOLS*NN; u += TPB){
    int cl = u/NN, i = u - cl*NN, c = p + PBLK*cl;
    if (c < 256){
      float s = 0.f;
      for (int k = 0; k < 64; k++) s += x[i*64+k]*W1[k*256+c];
      hL[u] = s;
    }
  }
  __syncthreads();
  gcn_bn_relu(hL, hT, b1, g1, bt1, ei, dinv, accL, colstat, p, tid);
}

// ---------------- enc2: GEMM2 hT@W2 + GCN/BN/ReLU -> h2T --------------------
__global__ __launch_bounds__(TPB, 1) void enc2(
    const int* __restrict__ ei,
    const float* __restrict__ W2, const float* __restrict__ b2,
    const float* __restrict__ g2, const float* __restrict__ bt2,
    float* __restrict__ ws)
{
  const int tid = threadIdx.x, p = blockIdx.x;
  const float* hT = ws + WS_HT;
  float* h2T = ws + WS_H2T;
  __shared__ float dinv[NN];
  __shared__ float accL[NCOLS*NN];
  __shared__ float hL[NCOLS*NN];
  __shared__ float colstat[2*NCOLS];

  mk_dinv(ei, accL, dinv, tid);
  for (int u = tid; u < 20*NCOLS; u += TPB){
    int cl = u/20, iq = u - cl*20, c = p + PBLK*cl;
    if (c < 256){
      int i0 = 4*iq;
      float a0=0.f,a1=0.f,a2=0.f,a3=0.f;
      for (int k = 0; k < 256; k++){
        float wv = W2[k*256+c];
        float4 hv = *(const float4*)&hT[k*NN+i0];
        a0 += hv.x*wv; a1 += hv.y*wv; a2 += hv.z*wv; a3 += hv.w*wv;
      }
      hL[cl*NN+i0+0]=a0; hL[cl*NN+i0+1]=a1; hL[cl*NN+i0+2]=a2; hL[cl*NN+i0+3]=a3;
    }
  }
  __syncthreads();
  gcn_bn_relu(hL, h2T, b2, g2, bt2, ei, dinv, accL, colstat, p, tid);
}

// ---------------- enc3: pool -> z -> t1 -> pair logits -> Bm ----------------
__global__ __launch_bounds__(TPB, 1) void enc3(
    const float* __restrict__ eps,
    const float* __restrict__ Wmu, const float* __restrict__ bmu,
    const float* __restrict__ Wlv, const float* __restrict__ blv,
    const float* __restrict__ We1, const float* __restrict__ be1,
    const float* __restrict__ We2, const float* __restrict__ be2,
    float* __restrict__ ws)
{
  const int tid = threadIdx.x, p = blockIdx.x;
  const float* h2T = ws + WS_H2T;
  float* Bm = ws + WS_BM;
  __shared__ float gv[256], zv[128], t1v[256];

  for (int c = tid; c < 256; c += TPB){
    const float* r = &h2T[c*NN];
    float s = 0.f;
    for (int i = 0; i < NN; i++) s += r[i];
    gv[c] = s*(1.0f/NN);
  }
  __syncthreads();
  for (int c = tid; c < 128; c += TPB){
    float smu = bmu[c], slv = blv[c];
    for (int k = 0; k < 256; k++){
      float g = gv[k];
      smu += g*Wmu[k*128+c];
      slv += g*Wlv[k*128+c];
    }
    slv = fminf(fmaxf(slv, -4.f), 4.f);
    zv[c] = smu + eps[c]*expf(0.5f*slv);
  }
  __syncthreads();
  for (int c = tid; c < 256; c += TPB){
    float s = be1[c];
    for (int k = 0; k < 128; k++) s += zv[k]*We1[k*256+c];
    t1v[c] = fmaxf(s, 0.f);
  }
  __syncthreads();
  for (int r = 0; r < 4; r++){
    int i = p + PBLK*r;                                // rows p, p+20, p+40, p+60
    if (tid == 0) Bm[i*NN+i] = 1.0f;                   // diag forced to 1
    for (int j = i+1+tid; j < NN; j += TPB){
      int off = i*(2*NN-1-i)/2 + (j-i-1);              // triu(k=1) flat index
      float s = be2[off];
      for (int k = 0; k < 256; k++) s += t1v[k]*We2[k*3160+off];
      float sg = 1.0f/(1.0f + expf(-s));
      Bm[i*NN+j] = sg;
      Bm[j*NN+i] = sg;
    }
  }
}

// ---------------- prep: Aw (float A), degA, degB ---------------------------
__global__ __launch_bounds__(TPB, 1) void prep(
    const int* __restrict__ adj, float* __restrict__ ws)
{
  const int tid = threadIdx.x, p = blockIdx.x;
  const float* Bm = ws + WS_BM;
  float* Aw = ws + WS_AW;
  float* degA = ws + WS_DEGA;
  float* degB = ws + WS_DEGB;
  __shared__ float AwL[4*NN];

  // rows 4p..4p+3 of A: 320 threads = 4*80 exactly
  int r = tid/NN, j = tid - r*NN, row = 4*p + r;
  float v = (((adj[row*NN+j] | adj[j*NN+row]) != 0) || (row == j)) ? 1.f : 0.f;
  AwL[r*NN+j] = v;
  Aw[row*NN+j] = v;
  __syncthreads();
  if (tid < 4){
    // degA: same chunked accumulation order as r8's E5
    const float4* ar = (const float4*)&AwL[tid*NN];
    float dg = 0.f;
    #pragma unroll
    for (int c = 0; c < 20; c++){
      float4 a = ar[c];
      dg += (a.x+a.y)+(a.z+a.w);
    }
    degA[4*p+tid] = dg;
  } else if (tid < 8){
    int a0 = 4*p + (tid-4);
    const float4* br = (const float4*)&Bm[a0*NN];
    float dg = 0.f;
    #pragma unroll
    for (int c = 0; c < 20; c++){
      float4 b = br[c];
      dg += (b.x+b.y)+(b.z+b.w);
    }
    degB[a0] = dg;
  }
}

// ---------------- mpm_step: one MPM iteration (t is a kernel arg) -----------
__global__ __launch_bounds__(TPB, 1) void mpm_step(int t, float* __restrict__ ws)
{
  const int tid = threadIdx.x, p = blockIdx.x;
  float* flags = ws + WS_FLAGS;
  float* Xb0   = ws + WS_XB0;
  float* Xb1   = ws + WS_XB1;
  const float* Bm   = ws + WS_BM;
  const float* Aw   = ws + WS_AW;
  const float* degA = ws + WS_DEGA;
  const float* degB = ws + WS_DEGB;

  const int w  = tid >> 6;
  const int l  = tid & 63;
  const int il = 16*w + (l & 15);    // this lane's row i
  const int ae = l >> 4;             // local column index 0..3
  const int al = 4*p + ae;           // this lane's column a

  __shared__ float Xs[NN*RP];        // X tile, row-major [i][a], pad 84
  __shared__ float MtL[4*RP];        // M^T (own 4 columns)
  __shared__ float red[8];

  // register caches (values identical to r8's E5)
  f4 Bf[20], Af[20];
  const f4* brow = (const f4*)&Bm[al*NN];
  const f4* arow = (const f4*)&Aw[il*NN];
  #pragma unroll
  for (int c = 0; c < 20; c++){ Bf[c] = brow[c]; Af[c] = arow[c]; }
  {
    int dc = al >> 2, de = al & 3;   // b==a exclusion (valid since X,B >= 0)
    if      (de == 0) Bf[dc].x = 0.f;
    else if (de == 1) Bf[dc].y = 0.f;
    else if (de == 2) Bf[dc].z = 0.f;
    else              Bf[dc].w = 0.f;
  }
  const float ns = 1.0f/(fabsf(degA[il]-degB[al])+1.0f);

  // sc = 1/||R_t|| from flags[t-1] (fixed-order reduction, r8-identical)
  float sc = 1.0f;
  if (t > 0){
    float fv = (l < PBLK) ? flags[(t-1)*32 + l] : 0.f;
    sc = 1.0f/sqrtf(wave_sum(fv));
  }

  // stage X(t) into LDS (linear, conflict-free; t=0: X0 = 1/n)
  if (t == 0){
    for (int u = tid; u < NN*RP; u += TPB) Xs[u] = 1.0f/NN;
  } else {
    const f4* S4 = (const f4*)(((t-1)&1) ? Xb1 : Xb0);
    #pragma unroll
    for (int c5 = 0; c5 < 5; c5++){
      int q = tid + TPB*c5;
      f4 v4 = S4[q];
      int i = q/20, a0 = 4*(q - 20*i);
      *(f4*)&Xs[i*RP + a0] = v4;
    }
  }
  __syncthreads();

  // M[il][al] = max_{b != al} X[il][b]*B[al][b]
  float m = 0.f;
  #pragma unroll
  for (int c = 0; c < 20; c++){
    float4 xv = *(const float4*)&Xs[il*RP+4*c];
    float p0 = xv.x*Bf[c].x, p1 = xv.y*Bf[c].y, p2 = xv.z*Bf[c].z, p3 = xv.w*Bf[c].w;
    m = fmaxf(m, fmaxf(fmaxf(p0,p1), fmaxf(p2,p3)));
  }
  float xnode = Xs[il*RP+al];
  MtL[ae*RP+il] = m;
  __syncthreads();

  // edge[il][al] = sum_j A[il][j]*M[j][al] - M[il][al]   (A[i][i] = 1)
  float e0=0.f,e1=0.f,e2=0.f,e3=0.f;
  #pragma unroll
  for (int c = 0; c < 20; c++){
    float4 mv = *(const float4*)&MtL[ae*RP+4*c];
    e0 += Af[c].x*mv.x; e1 += Af[c].y*mv.y; e2 += Af[c].z*mv.z; e3 += Af[c].w*mv.w;
  }
  float edge = ((e0+e1)+(e2+e3)) - m;
  float xn = sc*(ns*xnode + edge);    // R_{t+1} = f(R_t / ||R_t||)

  // write X(t+1) (plain cached store; kernel boundary publishes it)
  float* Xdst = (t&1) ? Xb1 : Xb0;
  Xdst[il*NN+al] = xn;

  // per-block norm partial -> flags[t] (r8-identical reduction order)
  float v = wave_sum(xn*xn);
  if (l == 0) red[w] = v;
  __syncthreads();
  if (tid == 0){
    float part = ((red[0]+red[1])+(red[2]+red[3]))+red[4];
    flags[t*32+p] = part;
  }
}

// ---------------- fin: final normalization -> out ---------------------------
__global__ __launch_bounds__(TPB, 1) void fin(
    const float* __restrict__ ws, float* __restrict__ out)
{
  const int tid = threadIdx.x, p = blockIdx.x;
  const float* flags = ws + WS_FLAGS;
  const float* X49   = ws + WS_XB1;   // t=49 wrote Xb1 (49&1 == 1)
  const int w  = tid >> 6;
  const int l  = tid & 63;
  const int il = 16*w + (l & 15);
  const int ae = l >> 4;
  const int al = 4*p + ae;
  float fv = (l < PBLK) ? flags[49*32 + l] : 0.f;
  float scf = 1.0f/sqrtf(wave_sum(fv));
  out[il*NN+al] = X49[il*NN+al]*scf;
}

extern "C" void kernel_launch(void* const* d_in, const int* in_sizes, int n_in,
                              void* d_out, int out_size, void* d_ws, size_t ws_size,
                              hipStream_t stream)
{
  (void)in_sizes; (void)n_in; (void)out_size; (void)ws_size;
  float* ws = (float*)d_ws;
  enc1<<<PBLK, TPB, 0, stream>>>(
      (const float*)d_in[0], (const int*)d_in[1],
      (const float*)d_in[4], (const float*)d_in[5],
      (const float*)d_in[6], (const float*)d_in[7], ws);
  enc2<<<PBLK, TPB, 0, stream>>>(
      (const int*)d_in[1],
      (const float*)d_in[8], (const float*)d_in[9],
      (const float*)d_in[10], (const float*)d_in[11], ws);
  enc3<<<PBLK, TPB, 0, stream>>>(
      (const float*)d_in[3],
      (const float*)d_in[12], (const float*)d_in[13],
      (const float*)d_in[14], (const float*)d_in[15],
      (const float*)d_in[16], (const float*)d_in[17],
      (const float*)d_in[18], (const float*)d_in[19], ws);
  prep<<<PBLK, TPB, 0, stream>>>((const int*)d_in[2], ws);
  for (int t = 0; t < 50; t++)
    mpm_step<<<PBLK, TPB, 0, stream>>>(t, ws);
  fin<<<PBLK, TPB, 0, stream>>>(ws, (float*)d_out);
}